// Round 8
// baseline (669.469 us; speedup 1.0000x reference)
//
#include <hip/hip_runtime.h>
#include <cstdint>
#include <cstddef>

// ---------------------------------------------------------------------------
// GCN 3-layer + FC head. Round 8: fused spmv+GEMM layer kernel (kills the
// 150MB SX round-trip). Gather -> swizzled LDS -> MFMA, one kernel per layer.
// ---------------------------------------------------------------------------

typedef __attribute__((ext_vector_type(4))) float f32x4;
typedef __attribute__((ext_vector_type(8))) short bf16x8;
typedef unsigned short u16;

#define G_CHUNKS 256

__device__ __forceinline__ float bf2f(unsigned int u) {
  union { unsigned int i; float f; } v;
  v.i = u << 16;
  return v.f;
}
__device__ __forceinline__ u16 f2bf(float f) {
  union { float f; unsigned int i; } v;
  v.f = f;
  unsigned int i = v.i;
  return (u16)((i + 0x7FFFu + ((i >> 16) & 1u)) >> 16);  // RNE
}

// ---------------- CSR build: counting sort by dst bucket ----------------

__global__ __launch_bounds__(256) void k_hist(const int* __restrict__ ei,
                                              int* __restrict__ ghist,
                                              int E, int B, int chunk) {
  __shared__ int h[512];
  for (int t = threadIdx.x; t < B; t += 256) h[t] = 0;
  __syncthreads();
  const int g = blockIdx.x;
  const int beg = g * chunk;
  const int end = min(beg + chunk, E);
  for (int e = beg + threadIdx.x; e < end; e += 256)
    atomicAdd(&h[ei[E + e] >> 8], 1);
  __syncthreads();
  for (int t = threadIdx.x; t < B; t += 256) ghist[(size_t)t * G_CHUNKS + g] = h[t];
}

__global__ __launch_bounds__(256) void k_hscan(int* __restrict__ ghist,
                                               int* __restrict__ btot) {
  __shared__ int sm[256];
  int* p = ghist + (size_t)blockIdx.x * G_CHUNKS;
  const int t = threadIdx.x;
  int v = p[t];
  sm[t] = v;
  __syncthreads();
  for (int off = 1; off < 256; off <<= 1) {
    int u = (t >= off) ? sm[t - off] : 0;
    __syncthreads();
    sm[t] += u;
    __syncthreads();
  }
  p[t] = sm[t] - v;                     // exclusive
  if (t == 255) btot[blockIdx.x] = sm[255];
}

__global__ __launch_bounds__(512) void k_bscan(const int* __restrict__ btot,
                                               int* __restrict__ boff, int B,
                                               int* __restrict__ rowptr, int n,
                                               int E, int tot) {
  __shared__ int sm[512];
  const int t = threadIdx.x;
  int v = (t < B) ? btot[t] : 0;
  sm[t] = v;
  __syncthreads();
  for (int off = 1; off < 512; off <<= 1) {
    int u = (t >= off) ? sm[t - off] : 0;
    __syncthreads();
    sm[t] += u;
    __syncthreads();
  }
  if (t < B) boff[t] = sm[t] - v;       // exclusive
  if (t == 0) {
    boff[B] = E;
    rowptr[n] = tot;
  }
}

__global__ __launch_bounds__(256) void k_scatter(const int* __restrict__ ei,
                                                 const int* __restrict__ ghist,
                                                 const int* __restrict__ boff,
                                                 unsigned int* __restrict__ ebuf,
                                                 int E, int B, int chunk) {
  __shared__ int off[512];
  const int g = blockIdx.x;
  for (int t = threadIdx.x; t < B; t += 256)
    off[t] = boff[t] + ghist[(size_t)t * G_CHUNKS + g];
  __syncthreads();
  const int beg = g * chunk;
  const int end = min(beg + chunk, E);
  for (int e = beg + threadIdx.x; e < end; e += 256) {
    int s = ei[e];
    int d = ei[E + e];
    int pos = atomicAdd(&off[d >> 8], 1);
    ebuf[pos] = ((unsigned int)s << 8) | (unsigned int)(d & 255);
  }
}

__global__ __launch_bounds__(256) void k_cfill(const unsigned int* __restrict__ ebuf,
                                               const int* __restrict__ boff,
                                               int* __restrict__ rowptr,
                                               int* __restrict__ col,
                                               float* __restrict__ dis, int n) {
  __shared__ int cnt[256];
  __shared__ int fl[256];
  const int b = blockIdx.x;
  const int t = threadIdx.x;
  const int beg = boff[b];
  const int end = boff[b + 1];
  const int node0 = b << 8;
  const int nn = min(256, n - node0);
  cnt[t] = 0;
  __syncthreads();
  for (int e = beg + t; e < end; e += 256)
    atomicAdd(&cnt[ebuf[e] & 255u], 1);
  __syncthreads();
  int v = cnt[t];
  __shared__ int sm[256];
  sm[t] = v;
  __syncthreads();
  for (int off = 1; off < 256; off <<= 1) {
    int u = (t >= off) ? sm[t - off] : 0;
    __syncthreads();
    sm[t] += u;
    __syncthreads();
  }
  if (t < nn) {
    int excl = sm[t] - v;
    int rbase = beg + node0 + t + excl;   // earlier buckets' edges + self-loops
    int i = node0 + t;
    rowptr[i] = rbase;
    col[rbase] = i;                        // self-loop first
    fl[t] = rbase + 1;
    dis[i] = rsqrtf((float)(v + 1));
  }
  __syncthreads();
  for (int e = beg + t; e < end; e += 256) {
    unsigned int pk = ebuf[e];
    int pos = atomicAdd(&fl[pk & 255u], 1);
    col[pos] = (int)(pk >> 8);
  }
}

// ---------------- dtype prep ----------------

__global__ __launch_bounds__(256) void k_cvt(const float* __restrict__ src,
                                             u16* __restrict__ dst, int total8) {
  int i = blockIdx.x * 256 + threadIdx.x;
  if (i >= total8) return;
  size_t b = (size_t)i * 8;
  float4 a0 = *(const float4*)(src + b);
  float4 a1 = *(const float4*)(src + b + 4);
  u16 o[8] = {f2bf(a0.x), f2bf(a0.y), f2bf(a0.z), f2bf(a0.w),
              f2bf(a1.x), f2bf(a1.y), f2bf(a1.z), f2bf(a1.w)};
  *(ulonglong2*)(dst + b) = *(ulonglong2*)o;
}

// blocks 0..767: WT[z][nr][k] = bf16(W_z[k][nr])
// blocks 768..770: bias sums; blocks 771..834: fcT[nr][k] = bf16(fcw[k][nr])
__global__ __launch_bounds__(128) void k_prep(const float* __restrict__ w0,
                                              const float* __restrict__ w1,
                                              const float* __restrict__ w2,
                                              const float* __restrict__ w3,
                                              const float* __restrict__ w4,
                                              const float* __restrict__ w5,
                                              const float* __restrict__ g1,
                                              const float* __restrict__ l1,
                                              const float* __restrict__ g2,
                                              const float* __restrict__ l2,
                                              const float* __restrict__ g3,
                                              const float* __restrict__ l3,
                                              const float* __restrict__ fcw,
                                              u16* __restrict__ wt,
                                              float* __restrict__ bias,
                                              u16* __restrict__ fcT) {
  int bx = blockIdx.x;
  if (bx < 768) {
    int z = bx >> 7, nr = bx & 127, k = threadIdx.x;
    const float* Ws[6] = {w0, w1, w2, w3, w4, w5};
    wt[(size_t)z * 16384 + nr * 128 + k] = f2bf(Ws[z][k * 128 + nr]);
  } else if (bx < 771) {
    int t = (bx - 768) * 128 + threadIdx.x;
    if (t < 384) {
      const float* gs[3] = {g1, g2, g3};
      const float* ls[3] = {l1, l2, l3};
      bias[t] = gs[t >> 7][t & 127] + ls[t >> 7][t & 127];
    }
  } else {
    int nr = bx - 771;                 // 0..63
    int k = threadIdx.x;
    fcT[nr * 128 + k] = f2bf(fcw[k * 64 + nr]);
  }
}

// ---------------------------------------------------------------------------
// Fused GCN layer:  out = lrelu( (S@A)@W0 + A@W1 + bias )
// Phase 1: per-wave gather of 32 rows' SX (fp32 acc) -> bf16 -> swizzled LDS.
// Phase 2: MFMA, A0 from LDS, A1 direct from global, W from WT.
// LDS swizzle: byte_in_row ^= (row&7)<<4. Write: 64 lanes same row -> banks
// distinct. Read b128: 16 rows x 4 kg -> 2 lanes/bank (free, m136).
// gfx950 16x16x32 mapping: A/B lane l -> row/col l&15, k (l>>4)*8+e;
//                          D lane l -> col l&15, row (l>>4)*4+e.
// NOT in-place safe: blocks write out while others gather-read Ab.
// ---------------------------------------------------------------------------
__global__ __launch_bounds__(256, 4) void k_layer(const int* __restrict__ rowptr,
                                                  const int* __restrict__ col,
                                                  const float* __restrict__ dis,
                                                  const u16* __restrict__ Ab,
                                                  const u16* __restrict__ W0T,
                                                  const u16* __restrict__ W1T,
                                                  const float* __restrict__ bias,
                                                  u16* __restrict__ outb,
                                                  float* __restrict__ outf,
                                                  int n) {
  __shared__ char ldsb[128 * 256];     // 128 rows x 128 bf16, swizzled
  const int lane = threadIdx.x & 63;
  const int wv = threadIdx.x >> 6;
  const int row0 = blockIdx.x * 128;

  // ---- phase 1: gather SX for this block's rows ----
  for (int t = 0; t < 32; ++t) {
    const int li = wv * 32 + t;        // local row
    const int i = row0 + li;
    float ax = 0.f, ay = 0.f;
    if (i < n) {
      int j = rowptr[i];
      const int end = rowptr[i + 1];
      for (; (j & 3) && j < end; ++j) {
        int c0 = col[j];
        float w0 = dis[c0];
        unsigned int q0 = *(const unsigned int*)(Ab + (size_t)c0 * 128 + lane * 2);
        ax = fmaf(bf2f(q0 & 0xffffu), w0, ax);
        ay = fmaf(bf2f(q0 >> 16), w0, ay);
      }
      for (; j + 3 < end; j += 4) {
        int4 c4 = *(const int4*)(col + j);
        float w0 = dis[c4.x], w1 = dis[c4.y], w2 = dis[c4.z], w3 = dis[c4.w];
        unsigned int q0 = *(const unsigned int*)(Ab + (size_t)c4.x * 128 + lane * 2);
        unsigned int q1 = *(const unsigned int*)(Ab + (size_t)c4.y * 128 + lane * 2);
        unsigned int q2 = *(const unsigned int*)(Ab + (size_t)c4.z * 128 + lane * 2);
        unsigned int q3 = *(const unsigned int*)(Ab + (size_t)c4.w * 128 + lane * 2);
        ax = fmaf(bf2f(q0 & 0xffffu), w0, ax);
        ay = fmaf(bf2f(q0 >> 16), w0, ay);
        ax = fmaf(bf2f(q1 & 0xffffu), w1, ax);
        ay = fmaf(bf2f(q1 >> 16), w1, ay);
        ax = fmaf(bf2f(q2 & 0xffffu), w2, ax);
        ay = fmaf(bf2f(q2 >> 16), w2, ay);
        ax = fmaf(bf2f(q3 & 0xffffu), w3, ax);
        ay = fmaf(bf2f(q3 >> 16), w3, ay);
      }
      for (; j < end; ++j) {
        int c0 = col[j];
        float w0 = dis[c0];
        unsigned int q0 = *(const unsigned int*)(Ab + (size_t)c0 * 128 + lane * 2);
        ax = fmaf(bf2f(q0 & 0xffffu), w0, ax);
        ay = fmaf(bf2f(q0 >> 16), w0, ay);
      }
      float di = dis[i];
      ax *= di;
      ay *= di;
    }
    unsigned int o = (unsigned int)f2bf(ax) | ((unsigned int)f2bf(ay) << 16);
    const int kbyte = lane * 4;
    *(unsigned int*)(ldsb + li * 256 + (kbyte ^ ((li & 7) << 4))) = o;
  }
  __syncthreads();

  // ---- phase 2: MFMA ----
  const int r = lane & 15;
  const int kg = lane >> 4;

  f32x4 acc[2][8];
#pragma unroll
  for (int a = 0; a < 2; ++a)
#pragma unroll
    for (int j = 0; j < 8; ++j) acc[a][j] = (f32x4){0.f, 0.f, 0.f, 0.f};

  const int lr0 = wv * 32 + r;          // local rows of the two A-fragments
  const int lr1 = wv * 32 + 16 + r;
  const int ra0 = min(row0 + lr0, n - 1);
  const int ra1 = min(row0 + lr1, n - 1);
  const int sw = (r & 7) << 4;          // same for lr0/lr1 (+16 keeps &7)

  // p=0: A0 = SX from LDS, weights W0T
#pragma unroll
  for (int kk = 0; kk < 4; ++kk) {
    const int kb = kk * 64 + kg * 16;   // byte offset of 8-bf16 fragment
    bf16x8 a0 = *(const bf16x8*)(ldsb + lr0 * 256 + (kb ^ sw));
    bf16x8 a1 = *(const bf16x8*)(ldsb + lr1 * 256 + (kb ^ sw));
    const int k0 = kk * 32 + kg * 8;
#pragma unroll
    for (int j = 0; j < 8; ++j) {
      bf16x8 b = *(const bf16x8*)(W0T + (size_t)(j * 16 + r) * 128 + k0);
      acc[0][j] = __builtin_amdgcn_mfma_f32_16x16x32_bf16(a0, b, acc[0][j], 0, 0, 0);
      acc[1][j] = __builtin_amdgcn_mfma_f32_16x16x32_bf16(a1, b, acc[1][j], 0, 0, 0);
    }
  }
  // p=1: A1 = prev features direct from global, weights W1T
#pragma unroll
  for (int kk = 0; kk < 4; ++kk) {
    const int k0 = kk * 32 + kg * 8;
    bf16x8 a0 = *(const bf16x8*)(Ab + (size_t)ra0 * 128 + k0);
    bf16x8 a1 = *(const bf16x8*)(Ab + (size_t)ra1 * 128 + k0);
#pragma unroll
    for (int j = 0; j < 8; ++j) {
      bf16x8 b = *(const bf16x8*)(W1T + (size_t)(j * 16 + r) * 128 + k0);
      acc[0][j] = __builtin_amdgcn_mfma_f32_16x16x32_bf16(a0, b, acc[0][j], 0, 0, 0);
      acc[1][j] = __builtin_amdgcn_mfma_f32_16x16x32_bf16(a1, b, acc[1][j], 0, 0, 0);
    }
  }

#pragma unroll
  for (int rf = 0; rf < 2; ++rf)
#pragma unroll
    for (int e = 0; e < 4; ++e) {
      const int row = row0 + wv * 32 + rf * 16 + kg * 4 + e;
      if (row >= n) continue;
#pragma unroll
      for (int j = 0; j < 8; ++j) {
        const int c = j * 16 + r;
        float v = acc[rf][j][e] + bias[c];
        v = (v > 0.f) ? v : 0.01f * v;
        if (outf) outf[(size_t)row * 128 + c] = v;
        if (outb) outb[(size_t)row * 128 + c] = f2bf(v);
      }
    }
}

// ---------------------------------------------------------------------------
// FC head via MFMA: y = h @ fcw + fcb. hb3 bf16 [M,128], fcT bf16 [64][128].
// ---------------------------------------------------------------------------
__global__ __launch_bounds__(256) void k_fc_mfma(const u16* __restrict__ hb3,
                                                 const u16* __restrict__ fcT,
                                                 const float* __restrict__ fcb,
                                                 float* __restrict__ y, int M) {
  const int lane = threadIdx.x & 63;
  const int wv = threadIdx.x >> 6;
  const int row0 = blockIdx.x * 128 + wv * 32;
  const int r = lane & 15;
  const int kg = lane >> 4;

  f32x4 acc[2][4];
#pragma unroll
  for (int a = 0; a < 2; ++a)
#pragma unroll
    for (int j = 0; j < 4; ++j) acc[a][j] = (f32x4){0.f, 0.f, 0.f, 0.f};

  const int ra0 = min(row0 + r, M - 1);
  const int ra1 = min(row0 + 16 + r, M - 1);

#pragma unroll
  for (int kk = 0; kk < 4; ++kk) {
    const int k0 = kk * 32 + kg * 8;
    bf16x8 a0 = *(const bf16x8*)(hb3 + (size_t)ra0 * 128 + k0);
    bf16x8 a1 = *(const bf16x8*)(hb3 + (size_t)ra1 * 128 + k0);
#pragma unroll
    for (int j = 0; j < 4; ++j) {
      bf16x8 b = *(const bf16x8*)(fcT + (size_t)(j * 16 + r) * 128 + k0);
      acc[0][j] = __builtin_amdgcn_mfma_f32_16x16x32_bf16(a0, b, acc[0][j], 0, 0, 0);
      acc[1][j] = __builtin_amdgcn_mfma_f32_16x16x32_bf16(a1, b, acc[1][j], 0, 0, 0);
    }
  }

#pragma unroll
  for (int rf = 0; rf < 2; ++rf)
#pragma unroll
    for (int e = 0; e < 4; ++e) {
      const int row = row0 + rf * 16 + kg * 4 + e;
      if (row >= M) continue;
#pragma unroll
      for (int j = 0; j < 4; ++j) {
        const int c = j * 16 + r;
        y[(size_t)row * 64 + c] = acc[rf][j][e] + fcb[c];
      }
    }
}

// ---------------------------------------------------------------------------

extern "C" void kernel_launch(void* const* d_in, const int* in_sizes, int n_in,
                              void* d_out, int out_size, void* d_ws, size_t ws_size,
                              hipStream_t stream) {
  const float* X  = (const float*)d_in[0];
  const int* ei   = (const int*)d_in[1];
  const float* gw1 = (const float*)d_in[3];
  const float* gb1 = (const float*)d_in[4];
  const float* lw1 = (const float*)d_in[5];
  const float* lb1 = (const float*)d_in[6];
  const float* gw2 = (const float*)d_in[7];
  const float* gb2 = (const float*)d_in[8];
  const float* lw2 = (const float*)d_in[9];
  const float* lb2 = (const float*)d_in[10];
  const float* gw3 = (const float*)d_in[11];
  const float* gb3 = (const float*)d_in[12];
  const float* lw3 = (const float*)d_in[13];
  const float* lb3 = (const float*)d_in[14];
  const float* fcw = (const float*)d_in[15];
  const float* fcb = (const float*)d_in[16];

  const int n = in_sizes[0] / 128;
  const int E = in_sizes[1] / 2;
  const int tot = E + n;
  const int B = (n + 255) >> 8;        // buckets (<=512)
  const int chunk = (E + G_CHUNKS - 1) / G_CHUNKS;

  char* ws = (char*)d_ws;
  size_t off = 0;
  auto alloc = [&](size_t bytes) -> void* {
    void* p = ws + off;
    off = (off + bytes + 255) & ~(size_t)255;
    return p;
  };
  int* ghist   = (int*)alloc((size_t)B * G_CHUNKS * 4);
  int* btot    = (int*)alloc(512 * 4);
  int* boff    = (int*)alloc((size_t)(B + 1) * 4);
  int* rowptr  = (int*)alloc((size_t)(n + 1) * 4);
  float* dis   = (float*)alloc((size_t)n * 4);
  int* col     = (int*)alloc((size_t)tot * 4);
  unsigned int* ebuf = (unsigned int*)alloc((size_t)E * 4);
  u16* Xb      = (u16*)alloc((size_t)n * 128 * 2);   // X bf16; later h3 bf16
  u16* h2b     = (u16*)alloc((size_t)n * 128 * 2);   // layer-2 output ping
  u16* WT      = (u16*)alloc((size_t)6 * 16384 * 2);
  u16* fcT     = (u16*)alloc((size_t)64 * 128 * 2);
  float* bias  = (float*)alloc(384 * 4);          // total ~66 MB

  float* outh = (float*)d_out;                 // [n,128] final h fp32
  float* outy = outh + (size_t)n * 128;        // [n,64]  final y fp32
  u16* hb = (u16*)outy;  // bf16 h1 in y-region (exact fit); dead after layer 2
                         // reads; overwritten by k_fc_mfma at the very end.

  const int gM = (n + 127) / 128;
  const int g8 = (n * 128 / 8 + 255) / 256;

  // ---- CSR build (counting sort) ----
  k_hist<<<G_CHUNKS, 256, 0, stream>>>(ei, ghist, E, B, chunk);
  k_hscan<<<B, 256, 0, stream>>>(ghist, btot);
  k_bscan<<<1, 512, 0, stream>>>(btot, boff, B, rowptr, n, E, tot);
  k_scatter<<<G_CHUNKS, 256, 0, stream>>>(ei, ghist, boff, ebuf, E, B, chunk);
  k_cfill<<<B, 256, 0, stream>>>(ebuf, boff, rowptr, col, dis, n);

  // ---- dtype prep ----
  k_cvt<<<g8, 256, 0, stream>>>(X, Xb, n * 128 / 8);
  k_prep<<<835, 128, 0, stream>>>(gw1, lw1, gw2, lw2, gw3, lw3,
                                  gb1, lb1, gb2, lb2, gb3, lb3, fcw,
                                  WT, bias, fcT);

  // ---- fused layers (ping-pong, no in-place) ----
  // L1: Xb -> hb
  k_layer<<<gM, 256, 0, stream>>>(rowptr, col, dis, Xb,
                                  WT, WT + 16384, bias, hb, nullptr, n);
  // L2: hb -> h2b
  k_layer<<<gM, 256, 0, stream>>>(rowptr, col, dis, hb,
                                  WT + 2 * 16384, WT + 3 * 16384, bias + 128,
                                  h2b, nullptr, n);
  // L3: h2b -> outh (fp32) + Xb (bf16 for FC)
  k_layer<<<gM, 256, 0, stream>>>(rowptr, col, dis, h2b,
                                  WT + 4 * 16384, WT + 5 * 16384, bias + 256,
                                  Xb, outh, n);
  // ---- FC head via MFMA (reads bf16 h3 in Xb, writes y over hb) ----
  k_fc_mfma<<<gM, 256, 0, stream>>>(Xb, fcT, fcb, outy, n);
}

// Round 9
// 507.981 us; speedup vs baseline: 1.3179x; 1.3179x over previous
//
#include <hip/hip_runtime.h>
#include <cstdint>
#include <cstddef>

// ---------------------------------------------------------------------------
// GCN 3-layer + FC head. Round 9: revert round-8 fusion (occupancy killed the
// latency-bound gather). Round-7 split structure + spmv sharpening:
// pre-scaled features (no per-edge dis loads) + unroll-8 gather.
// ---------------------------------------------------------------------------

typedef __attribute__((ext_vector_type(4))) float f32x4;
typedef __attribute__((ext_vector_type(8))) short bf16x8;
typedef unsigned short u16;

#define G_CHUNKS 256

__device__ __forceinline__ float bf2f(unsigned int u) {
  union { unsigned int i; float f; } v;
  v.i = u << 16;
  return v.f;
}
__device__ __forceinline__ u16 f2bf(float f) {
  union { float f; unsigned int i; } v;
  v.f = f;
  unsigned int i = v.i;
  return (u16)((i + 0x7FFFu + ((i >> 16) & 1u)) >> 16);  // RNE
}

// ---------------- CSR build: counting sort by dst bucket ----------------

__global__ __launch_bounds__(256) void k_hist(const int* __restrict__ ei,
                                              int* __restrict__ ghist,
                                              int E, int B, int chunk) {
  __shared__ int h[512];
  for (int t = threadIdx.x; t < B; t += 256) h[t] = 0;
  __syncthreads();
  const int g = blockIdx.x;
  const int beg = g * chunk;
  const int end = min(beg + chunk, E);
  for (int e = beg + threadIdx.x; e < end; e += 256)
    atomicAdd(&h[ei[E + e] >> 8], 1);
  __syncthreads();
  for (int t = threadIdx.x; t < B; t += 256) ghist[(size_t)t * G_CHUNKS + g] = h[t];
}

__global__ __launch_bounds__(256) void k_hscan(int* __restrict__ ghist,
                                               int* __restrict__ btot) {
  __shared__ int sm[256];
  int* p = ghist + (size_t)blockIdx.x * G_CHUNKS;
  const int t = threadIdx.x;
  int v = p[t];
  sm[t] = v;
  __syncthreads();
  for (int off = 1; off < 256; off <<= 1) {
    int u = (t >= off) ? sm[t - off] : 0;
    __syncthreads();
    sm[t] += u;
    __syncthreads();
  }
  p[t] = sm[t] - v;                     // exclusive
  if (t == 255) btot[blockIdx.x] = sm[255];
}

__global__ __launch_bounds__(512) void k_bscan(const int* __restrict__ btot,
                                               int* __restrict__ boff, int B,
                                               int* __restrict__ rowptr, int n,
                                               int E, int tot) {
  __shared__ int sm[512];
  const int t = threadIdx.x;
  int v = (t < B) ? btot[t] : 0;
  sm[t] = v;
  __syncthreads();
  for (int off = 1; off < 512; off <<= 1) {
    int u = (t >= off) ? sm[t - off] : 0;
    __syncthreads();
    sm[t] += u;
    __syncthreads();
  }
  if (t < B) boff[t] = sm[t] - v;       // exclusive
  if (t == 0) {
    boff[B] = E;
    rowptr[n] = tot;
  }
}

__global__ __launch_bounds__(256) void k_scatter(const int* __restrict__ ei,
                                                 const int* __restrict__ ghist,
                                                 const int* __restrict__ boff,
                                                 unsigned int* __restrict__ ebuf,
                                                 int E, int B, int chunk) {
  __shared__ int off[512];
  const int g = blockIdx.x;
  for (int t = threadIdx.x; t < B; t += 256)
    off[t] = boff[t] + ghist[(size_t)t * G_CHUNKS + g];
  __syncthreads();
  const int beg = g * chunk;
  const int end = min(beg + chunk, E);
  for (int e = beg + threadIdx.x; e < end; e += 256) {
    int s = ei[e];
    int d = ei[E + e];
    int pos = atomicAdd(&off[d >> 8], 1);
    ebuf[pos] = ((unsigned int)s << 8) | (unsigned int)(d & 255);
  }
}

__global__ __launch_bounds__(256) void k_cfill(const unsigned int* __restrict__ ebuf,
                                               const int* __restrict__ boff,
                                               int* __restrict__ rowptr,
                                               int* __restrict__ col,
                                               float* __restrict__ dis, int n) {
  __shared__ int cnt[256];
  __shared__ int fl[256];
  const int b = blockIdx.x;
  const int t = threadIdx.x;
  const int beg = boff[b];
  const int end = boff[b + 1];
  const int node0 = b << 8;
  const int nn = min(256, n - node0);
  cnt[t] = 0;
  __syncthreads();
  for (int e = beg + t; e < end; e += 256)
    atomicAdd(&cnt[ebuf[e] & 255u], 1);
  __syncthreads();
  int v = cnt[t];
  __shared__ int sm[256];
  sm[t] = v;
  __syncthreads();
  for (int off = 1; off < 256; off <<= 1) {
    int u = (t >= off) ? sm[t - off] : 0;
    __syncthreads();
    sm[t] += u;
    __syncthreads();
  }
  if (t < nn) {
    int excl = sm[t] - v;
    int rbase = beg + node0 + t + excl;   // earlier buckets' edges + self-loops
    int i = node0 + t;
    rowptr[i] = rbase;
    col[rbase] = i;                        // self-loop first
    fl[t] = rbase + 1;
    dis[i] = rsqrtf((float)(v + 1));
  }
  __syncthreads();
  for (int e = beg + t; e < end; e += 256) {
    unsigned int pk = ebuf[e];
    int pos = atomicAdd(&fl[pk & 255u], 1);
    col[pos] = (int)(pk >> 8);
  }
}

// ---------------- dtype prep ----------------

// X fp32 -> Xb (bf16) and Xs (bf16, pre-scaled by dis[row]); 8 elems/thread.
__global__ __launch_bounds__(256) void k_cvt(const float* __restrict__ src,
                                             const float* __restrict__ dis,
                                             u16* __restrict__ dstb,
                                             u16* __restrict__ dsts, int total8) {
  int i = blockIdx.x * 256 + threadIdx.x;
  if (i >= total8) return;
  size_t b = (size_t)i * 8;
  float ds = dis[i >> 4];               // 16 threads x 8 elems = one 128-row
  float4 a0 = *(const float4*)(src + b);
  float4 a1 = *(const float4*)(src + b + 4);
  u16 ob[8] = {f2bf(a0.x), f2bf(a0.y), f2bf(a0.z), f2bf(a0.w),
               f2bf(a1.x), f2bf(a1.y), f2bf(a1.z), f2bf(a1.w)};
  u16 os[8] = {f2bf(a0.x * ds), f2bf(a0.y * ds), f2bf(a0.z * ds), f2bf(a0.w * ds),
               f2bf(a1.x * ds), f2bf(a1.y * ds), f2bf(a1.z * ds), f2bf(a1.w * ds)};
  *(ulonglong2*)(dstb + b) = *(ulonglong2*)ob;
  *(ulonglong2*)(dsts + b) = *(ulonglong2*)os;
}

// blocks 0..767: WT[z][nr][k] = bf16(W_z[k][nr])
// blocks 768..770: bias sums; blocks 771..834: fcT[nr][k] = bf16(fcw[k][nr])
__global__ __launch_bounds__(128) void k_prep(const float* __restrict__ w0,
                                              const float* __restrict__ w1,
                                              const float* __restrict__ w2,
                                              const float* __restrict__ w3,
                                              const float* __restrict__ w4,
                                              const float* __restrict__ w5,
                                              const float* __restrict__ g1,
                                              const float* __restrict__ l1,
                                              const float* __restrict__ g2,
                                              const float* __restrict__ l2,
                                              const float* __restrict__ g3,
                                              const float* __restrict__ l3,
                                              const float* __restrict__ fcw,
                                              u16* __restrict__ wt,
                                              float* __restrict__ bias,
                                              u16* __restrict__ fcT) {
  int bx = blockIdx.x;
  if (bx < 768) {
    int z = bx >> 7, nr = bx & 127, k = threadIdx.x;
    const float* Ws[6] = {w0, w1, w2, w3, w4, w5};
    wt[(size_t)z * 16384 + nr * 128 + k] = f2bf(Ws[z][k * 128 + nr]);
  } else if (bx < 771) {
    int t = (bx - 768) * 128 + threadIdx.x;
    if (t < 384) {
      const float* gs[3] = {g1, g2, g3};
      const float* ls[3] = {l1, l2, l3};
      bias[t] = gs[t >> 7][t & 127] + ls[t >> 7][t & 127];
    }
  } else {
    int nr = bx - 771;                 // 0..63
    int k = threadIdx.x;
    fcT[nr * 128 + k] = f2bf(fcw[k * 64 + nr]);
  }
}

// ---------------------------------------------------------------------------
// SXb[i] = bf16( dis[i] * sum_j Xs[col[j], :] )   (Xs is pre-scaled by dis)
// one wave/node; col via int4 pairs; 8 row-gathers outstanding.
// ---------------------------------------------------------------------------
__global__ __launch_bounds__(256, 4) void k_spmv_bf(const int* __restrict__ rowptr,
                                                    const int* __restrict__ col,
                                                    const float* __restrict__ dis,
                                                    const u16* __restrict__ Xs,
                                                    u16* __restrict__ SXb, int n) {
  const int wave = threadIdx.x >> 6;
  const int lane = threadIdx.x & 63;
  const int i = blockIdx.x * 4 + wave;
  if (i >= n) return;
  int j = rowptr[i];
  const int end = rowptr[i + 1];
  float ax = 0.f, ay = 0.f;

#define ROWQ(c) (*(const unsigned int*)(Xs + (size_t)(c) * 128 + lane * 2))
#define ACC(q)  do { unsigned int _q = (q); \
                     ax += bf2f(_q & 0xffffu); ay += bf2f(_q >> 16); } while (0)

  // peel to 16B alignment of col+j
  for (; (j & 3) && j < end; ++j) ACC(ROWQ(col[j]));
  for (; j + 7 < end; j += 8) {
    int4 c0 = *(const int4*)(col + j);
    int4 c1 = *(const int4*)(col + j + 4);
    unsigned int q0 = ROWQ(c0.x), q1 = ROWQ(c0.y), q2 = ROWQ(c0.z), q3 = ROWQ(c0.w);
    unsigned int q4 = ROWQ(c1.x), q5 = ROWQ(c1.y), q6 = ROWQ(c1.z), q7 = ROWQ(c1.w);
    ACC(q0); ACC(q1); ACC(q2); ACC(q3);
    ACC(q4); ACC(q5); ACC(q6); ACC(q7);
  }
  if (j + 3 < end) {
    int4 c0 = *(const int4*)(col + j);
    unsigned int q0 = ROWQ(c0.x), q1 = ROWQ(c0.y), q2 = ROWQ(c0.z), q3 = ROWQ(c0.w);
    ACC(q0); ACC(q1); ACC(q2); ACC(q3);
    j += 4;
  }
  for (; j < end; ++j) ACC(ROWQ(col[j]));
#undef ROWQ
#undef ACC

  float di = dis[i];
  ax *= di;
  ay *= di;
  unsigned int o = (unsigned int)f2bf(ax) | ((unsigned int)f2bf(ay) << 16);
  *(unsigned int*)(SXb + (size_t)i * 128 + lane * 2) = o;
}

// ---------------------------------------------------------------------------
// MFMA fused layer:  v = lrelu( A0@W0 + A1@W1 + bias )
// outb: bf16 v; outs: bf16 dis[row]*v (next layer's gather src); outf: fp32 v.
// A0,A1 bf16 row-major [M,128]; W0T,W1T bf16 [n][k]. No LDS.
// gfx950 16x16x32 mapping: A/B lane l -> row/col l&15, k (l>>4)*8+e;
//                          D lane l -> col l&15, row (l>>4)*4+e.
// In-place on A1 is safe: block reads only rows it later writes.
// ---------------------------------------------------------------------------
__global__ __launch_bounds__(256) void k_mfma(const u16* __restrict__ A0,
                                              const u16* __restrict__ A1,
                                              const u16* __restrict__ W0T,
                                              const u16* __restrict__ W1T,
                                              const float* __restrict__ bias,
                                              const float* __restrict__ dis,
                                              u16* __restrict__ outb,
                                              u16* __restrict__ outs,
                                              float* __restrict__ outf, int M) {
  const int lane = threadIdx.x & 63;
  const int wv = threadIdx.x >> 6;
  const int row0 = blockIdx.x * 128 + wv * 32;
  const int r = lane & 15;
  const int kg = lane >> 4;

  f32x4 acc[2][8];
#pragma unroll
  for (int a = 0; a < 2; ++a)
#pragma unroll
    for (int j = 0; j < 8; ++j) acc[a][j] = (f32x4){0.f, 0.f, 0.f, 0.f};

  const int ra0 = min(row0 + r, M - 1);
  const int ra1 = min(row0 + 16 + r, M - 1);

#pragma unroll
  for (int p = 0; p < 2; ++p) {
    const u16* A = p ? A1 : A0;
    const u16* WT = p ? W1T : W0T;
#pragma unroll
    for (int kk = 0; kk < 4; ++kk) {
      const int k0 = kk * 32 + kg * 8;
      bf16x8 a0 = *(const bf16x8*)(A + (size_t)ra0 * 128 + k0);
      bf16x8 a1 = *(const bf16x8*)(A + (size_t)ra1 * 128 + k0);
#pragma unroll
      for (int j = 0; j < 8; ++j) {
        bf16x8 b = *(const bf16x8*)(WT + (size_t)(j * 16 + r) * 128 + k0);
        acc[0][j] = __builtin_amdgcn_mfma_f32_16x16x32_bf16(a0, b, acc[0][j], 0, 0, 0);
        acc[1][j] = __builtin_amdgcn_mfma_f32_16x16x32_bf16(a1, b, acc[1][j], 0, 0, 0);
      }
    }
  }

#pragma unroll
  for (int rf = 0; rf < 2; ++rf)
#pragma unroll
    for (int e = 0; e < 4; ++e) {
      const int row = row0 + rf * 16 + kg * 4 + e;
      if (row >= M) continue;
      const float ds = outs ? dis[row] : 0.f;
#pragma unroll
      for (int j = 0; j < 8; ++j) {
        const int c = j * 16 + r;
        float v = acc[rf][j][e] + bias[c];
        v = (v > 0.f) ? v : 0.01f * v;
        if (outf) outf[(size_t)row * 128 + c] = v;
        if (outb) outb[(size_t)row * 128 + c] = f2bf(v);
        if (outs) outs[(size_t)row * 128 + c] = f2bf(v * ds);
      }
    }
}

// ---------------------------------------------------------------------------
// FC head via MFMA: y = h @ fcw + fcb. hb3 bf16 [M,128], fcT bf16 [64][128].
// ---------------------------------------------------------------------------
__global__ __launch_bounds__(256) void k_fc_mfma(const u16* __restrict__ hb3,
                                                 const u16* __restrict__ fcT,
                                                 const float* __restrict__ fcb,
                                                 float* __restrict__ y, int M) {
  const int lane = threadIdx.x & 63;
  const int wv = threadIdx.x >> 6;
  const int row0 = blockIdx.x * 128 + wv * 32;
  const int r = lane & 15;
  const int kg = lane >> 4;

  f32x4 acc[2][4];
#pragma unroll
  for (int a = 0; a < 2; ++a)
#pragma unroll
    for (int j = 0; j < 4; ++j) acc[a][j] = (f32x4){0.f, 0.f, 0.f, 0.f};

  const int ra0 = min(row0 + r, M - 1);
  const int ra1 = min(row0 + 16 + r, M - 1);

#pragma unroll
  for (int kk = 0; kk < 4; ++kk) {
    const int k0 = kk * 32 + kg * 8;
    bf16x8 a0 = *(const bf16x8*)(hb3 + (size_t)ra0 * 128 + k0);
    bf16x8 a1 = *(const bf16x8*)(hb3 + (size_t)ra1 * 128 + k0);
#pragma unroll
    for (int j = 0; j < 4; ++j) {
      bf16x8 b = *(const bf16x8*)(fcT + (size_t)(j * 16 + r) * 128 + k0);
      acc[0][j] = __builtin_amdgcn_mfma_f32_16x16x32_bf16(a0, b, acc[0][j], 0, 0, 0);
      acc[1][j] = __builtin_amdgcn_mfma_f32_16x16x32_bf16(a1, b, acc[1][j], 0, 0, 0);
    }
  }

#pragma unroll
  for (int rf = 0; rf < 2; ++rf)
#pragma unroll
    for (int e = 0; e < 4; ++e) {
      const int row = row0 + rf * 16 + kg * 4 + e;
      if (row >= M) continue;
#pragma unroll
      for (int j = 0; j < 4; ++j) {
        const int c = j * 16 + r;
        y[(size_t)row * 64 + c] = acc[rf][j][e] + fcb[c];
      }
    }
}

// ---------------------------------------------------------------------------

extern "C" void kernel_launch(void* const* d_in, const int* in_sizes, int n_in,
                              void* d_out, int out_size, void* d_ws, size_t ws_size,
                              hipStream_t stream) {
  const float* X  = (const float*)d_in[0];
  const int* ei   = (const int*)d_in[1];
  const float* gw1 = (const float*)d_in[3];
  const float* gb1 = (const float*)d_in[4];
  const float* lw1 = (const float*)d_in[5];
  const float* lb1 = (const float*)d_in[6];
  const float* gw2 = (const float*)d_in[7];
  const float* gb2 = (const float*)d_in[8];
  const float* lw2 = (const float*)d_in[9];
  const float* lb2 = (const float*)d_in[10];
  const float* gw3 = (const float*)d_in[11];
  const float* gb3 = (const float*)d_in[12];
  const float* lw3 = (const float*)d_in[13];
  const float* lb3 = (const float*)d_in[14];
  const float* fcw = (const float*)d_in[15];
  const float* fcb = (const float*)d_in[16];

  const int n = in_sizes[0] / 128;
  const int E = in_sizes[1] / 2;
  const int tot = E + n;
  const int B = (n + 255) >> 8;        // buckets (<=512)
  const int chunk = (E + G_CHUNKS - 1) / G_CHUNKS;

  char* ws = (char*)d_ws;
  size_t off = 0;
  auto alloc = [&](size_t bytes) -> void* {
    void* p = ws + off;
    off = (off + bytes + 255) & ~(size_t)255;
    return p;
  };
  int* ghist   = (int*)alloc((size_t)B * G_CHUNKS * 4);
  int* btot    = (int*)alloc(512 * 4);
  int* boff    = (int*)alloc((size_t)(B + 1) * 4);
  int* rowptr  = (int*)alloc((size_t)(n + 1) * 4);
  float* dis   = (float*)alloc((size_t)n * 4);
  int* col     = (int*)alloc((size_t)tot * 4);
  unsigned int* ebuf = (unsigned int*)alloc((size_t)E * 4);
  u16* Xb      = (u16*)alloc((size_t)n * 128 * 2);   // X bf16; later h3 bf16
  u16* Xs      = (u16*)alloc((size_t)n * 128 * 2);   // scaled gather src (per layer)
  u16* SXb     = (u16*)alloc((size_t)n * 128 * 2);
  u16* WT      = (u16*)alloc((size_t)6 * 16384 * 2);
  u16* fcT     = (u16*)alloc((size_t)64 * 128 * 2);
  float* bias  = (float*)alloc(384 * 4);          // total ~92 MB

  float* outh = (float*)d_out;                 // [n,128] final h fp32
  float* outy = outh + (size_t)n * 128;        // [n,64]  final y fp32
  u16* hb = (u16*)outy;  // bf16 h1/h2 ping in y-region (exact fit);
                         // overwritten by k_fc_mfma at the very end.

  const int gM = (n + 127) / 128;
  const int gW = (n + 3) / 4;
  const int g8 = (n * 128 / 8 + 255) / 256;

  // ---- CSR build (counting sort) ----
  k_hist<<<G_CHUNKS, 256, 0, stream>>>(ei, ghist, E, B, chunk);
  k_hscan<<<B, 256, 0, stream>>>(ghist, btot);
  k_bscan<<<1, 512, 0, stream>>>(btot, boff, B, rowptr, n, E, tot);
  k_scatter<<<G_CHUNKS, 256, 0, stream>>>(ei, ghist, boff, ebuf, E, B, chunk);
  k_cfill<<<B, 256, 0, stream>>>(ebuf, boff, rowptr, col, dis, n);

  // ---- dtype prep (k_cvt needs dis -> after cfill) ----
  k_cvt<<<g8, 256, 0, stream>>>(X, dis, Xb, Xs, n * 128 / 8);
  k_prep<<<835, 128, 0, stream>>>(gw1, lw1, gw2, lw2, gw3, lw3,
                                  gb1, lb1, gb2, lb2, gb3, lb3, fcw,
                                  WT, bias, fcT);

  // ---- layer 1: gather Xs -> SXb; h1 -> hb, h1s -> Xs (Xs dead after spmv) ----
  k_spmv_bf<<<gW, 256, 0, stream>>>(rowptr, col, dis, Xs, SXb, n);
  k_mfma<<<gM, 256, 0, stream>>>(SXb, Xb, WT, WT + 16384, bias, dis,
                                 hb, Xs, nullptr, n);
  // ---- layer 2: gather h1s -> SXb; h2 -> hb (in-place), h2s -> Xs ----
  k_spmv_bf<<<gW, 256, 0, stream>>>(rowptr, col, dis, Xs, SXb, n);
  k_mfma<<<gM, 256, 0, stream>>>(SXb, hb, WT + 2 * 16384, WT + 3 * 16384,
                                 bias + 128, dis, hb, Xs, nullptr, n);
  // ---- layer 3: gather h2s -> SXb; h3 fp32 -> outh, h3 bf16 -> Xb ----
  k_spmv_bf<<<gW, 256, 0, stream>>>(rowptr, col, dis, Xs, SXb, n);
  k_mfma<<<gM, 256, 0, stream>>>(SXb, hb, WT + 4 * 16384, WT + 5 * 16384,
                                 bias + 256, dis, Xb, nullptr, outh, n);
  // ---- FC head via MFMA (reads bf16 h3 in Xb, writes y over hb) ----
  k_fc_mfma<<<gM, 256, 0, stream>>>(Xb, fcT, fcb, outy, n);
}

// Round 10
// 470.777 us; speedup vs baseline: 1.4221x; 1.0790x over previous
//
#include <hip/hip_runtime.h>
#include <cstdint>
#include <cstddef>

// ---------------------------------------------------------------------------
// GCN 3-layer + FC head. Round 10: col-split k_mfma (grid x2 -> occupancy
// 12->24 waves/CU on the latency-bound GEMM). Buffer rotation, no in-place.
// ---------------------------------------------------------------------------

typedef __attribute__((ext_vector_type(4))) float f32x4;
typedef __attribute__((ext_vector_type(8))) short bf16x8;
typedef unsigned short u16;

#define G_CHUNKS 256

__device__ __forceinline__ float bf2f(unsigned int u) {
  union { unsigned int i; float f; } v;
  v.i = u << 16;
  return v.f;
}
__device__ __forceinline__ u16 f2bf(float f) {
  union { float f; unsigned int i; } v;
  v.f = f;
  unsigned int i = v.i;
  return (u16)((i + 0x7FFFu + ((i >> 16) & 1u)) >> 16);  // RNE
}

// ---------------- CSR build: counting sort by dst bucket ----------------

__global__ __launch_bounds__(256) void k_hist(const int* __restrict__ ei,
                                              int* __restrict__ ghist,
                                              int E, int B, int chunk) {
  __shared__ int h[512];
  for (int t = threadIdx.x; t < B; t += 256) h[t] = 0;
  __syncthreads();
  const int g = blockIdx.x;
  const int beg = g * chunk;
  const int end = min(beg + chunk, E);
  for (int e = beg + threadIdx.x; e < end; e += 256)
    atomicAdd(&h[ei[E + e] >> 8], 1);
  __syncthreads();
  for (int t = threadIdx.x; t < B; t += 256) ghist[(size_t)t * G_CHUNKS + g] = h[t];
}

__global__ __launch_bounds__(256) void k_hscan(int* __restrict__ ghist,
                                               int* __restrict__ btot) {
  __shared__ int sm[256];
  int* p = ghist + (size_t)blockIdx.x * G_CHUNKS;
  const int t = threadIdx.x;
  int v = p[t];
  sm[t] = v;
  __syncthreads();
  for (int off = 1; off < 256; off <<= 1) {
    int u = (t >= off) ? sm[t - off] : 0;
    __syncthreads();
    sm[t] += u;
    __syncthreads();
  }
  p[t] = sm[t] - v;                     // exclusive
  if (t == 255) btot[blockIdx.x] = sm[255];
}

__global__ __launch_bounds__(512) void k_bscan(const int* __restrict__ btot,
                                               int* __restrict__ boff, int B,
                                               int* __restrict__ rowptr, int n,
                                               int E, int tot) {
  __shared__ int sm[512];
  const int t = threadIdx.x;
  int v = (t < B) ? btot[t] : 0;
  sm[t] = v;
  __syncthreads();
  for (int off = 1; off < 512; off <<= 1) {
    int u = (t >= off) ? sm[t - off] : 0;
    __syncthreads();
    sm[t] += u;
    __syncthreads();
  }
  if (t < B) boff[t] = sm[t] - v;       // exclusive
  if (t == 0) {
    boff[B] = E;
    rowptr[n] = tot;
  }
}

__global__ __launch_bounds__(256) void k_scatter(const int* __restrict__ ei,
                                                 const int* __restrict__ ghist,
                                                 const int* __restrict__ boff,
                                                 unsigned int* __restrict__ ebuf,
                                                 int E, int B, int chunk) {
  __shared__ int off[512];
  const int g = blockIdx.x;
  for (int t = threadIdx.x; t < B; t += 256)
    off[t] = boff[t] + ghist[(size_t)t * G_CHUNKS + g];
  __syncthreads();
  const int beg = g * chunk;
  const int end = min(beg + chunk, E);
  for (int e = beg + threadIdx.x; e < end; e += 256) {
    int s = ei[e];
    int d = ei[E + e];
    int pos = atomicAdd(&off[d >> 8], 1);
    ebuf[pos] = ((unsigned int)s << 8) | (unsigned int)(d & 255);
  }
}

__global__ __launch_bounds__(256) void k_cfill(const unsigned int* __restrict__ ebuf,
                                               const int* __restrict__ boff,
                                               int* __restrict__ rowptr,
                                               int* __restrict__ col,
                                               float* __restrict__ dis, int n) {
  __shared__ int cnt[256];
  __shared__ int fl[256];
  const int b = blockIdx.x;
  const int t = threadIdx.x;
  const int beg = boff[b];
  const int end = boff[b + 1];
  const int node0 = b << 8;
  const int nn = min(256, n - node0);
  cnt[t] = 0;
  __syncthreads();
  for (int e = beg + t; e < end; e += 256)
    atomicAdd(&cnt[ebuf[e] & 255u], 1);
  __syncthreads();
  int v = cnt[t];
  __shared__ int sm[256];
  sm[t] = v;
  __syncthreads();
  for (int off = 1; off < 256; off <<= 1) {
    int u = (t >= off) ? sm[t - off] : 0;
    __syncthreads();
    sm[t] += u;
    __syncthreads();
  }
  if (t < nn) {
    int excl = sm[t] - v;
    int rbase = beg + node0 + t + excl;   // earlier buckets' edges + self-loops
    int i = node0 + t;
    rowptr[i] = rbase;
    col[rbase] = i;                        // self-loop first
    fl[t] = rbase + 1;
    dis[i] = rsqrtf((float)(v + 1));
  }
  __syncthreads();
  for (int e = beg + t; e < end; e += 256) {
    unsigned int pk = ebuf[e];
    int pos = atomicAdd(&fl[pk & 255u], 1);
    col[pos] = (int)(pk >> 8);
  }
}

// ---------------- dtype prep ----------------

// X fp32 -> Xb (bf16) and Xs (bf16, pre-scaled by dis[row]); 8 elems/thread.
__global__ __launch_bounds__(256) void k_cvt(const float* __restrict__ src,
                                             const float* __restrict__ dis,
                                             u16* __restrict__ dstb,
                                             u16* __restrict__ dsts, int total8) {
  int i = blockIdx.x * 256 + threadIdx.x;
  if (i >= total8) return;
  size_t b = (size_t)i * 8;
  float ds = dis[i >> 4];               // 16 threads x 8 elems = one 128-row
  float4 a0 = *(const float4*)(src + b);
  float4 a1 = *(const float4*)(src + b + 4);
  u16 ob[8] = {f2bf(a0.x), f2bf(a0.y), f2bf(a0.z), f2bf(a0.w),
               f2bf(a1.x), f2bf(a1.y), f2bf(a1.z), f2bf(a1.w)};
  u16 os[8] = {f2bf(a0.x * ds), f2bf(a0.y * ds), f2bf(a0.z * ds), f2bf(a0.w * ds),
               f2bf(a1.x * ds), f2bf(a1.y * ds), f2bf(a1.z * ds), f2bf(a1.w * ds)};
  *(ulonglong2*)(dstb + b) = *(ulonglong2*)ob;
  *(ulonglong2*)(dsts + b) = *(ulonglong2*)os;
}

// blocks 0..767: WT[z][nr][k] = bf16(W_z[k][nr])
// blocks 768..770: bias sums; blocks 771..834: fcT[nr][k] = bf16(fcw[k][nr])
__global__ __launch_bounds__(128) void k_prep(const float* __restrict__ w0,
                                              const float* __restrict__ w1,
                                              const float* __restrict__ w2,
                                              const float* __restrict__ w3,
                                              const float* __restrict__ w4,
                                              const float* __restrict__ w5,
                                              const float* __restrict__ g1,
                                              const float* __restrict__ l1,
                                              const float* __restrict__ g2,
                                              const float* __restrict__ l2,
                                              const float* __restrict__ g3,
                                              const float* __restrict__ l3,
                                              const float* __restrict__ fcw,
                                              u16* __restrict__ wt,
                                              float* __restrict__ bias,
                                              u16* __restrict__ fcT) {
  int bx = blockIdx.x;
  if (bx < 768) {
    int z = bx >> 7, nr = bx & 127, k = threadIdx.x;
    const float* Ws[6] = {w0, w1, w2, w3, w4, w5};
    wt[(size_t)z * 16384 + nr * 128 + k] = f2bf(Ws[z][k * 128 + nr]);
  } else if (bx < 771) {
    int t = (bx - 768) * 128 + threadIdx.x;
    if (t < 384) {
      const float* gs[3] = {g1, g2, g3};
      const float* ls[3] = {l1, l2, l3};
      bias[t] = gs[t >> 7][t & 127] + ls[t >> 7][t & 127];
    }
  } else {
    int nr = bx - 771;                 // 0..63
    int k = threadIdx.x;
    fcT[nr * 128 + k] = f2bf(fcw[k * 64 + nr]);
  }
}

// ---------------------------------------------------------------------------
// SXb[i] = bf16( dis[i] * sum_j Xs[col[j], :] )   (Xs is pre-scaled by dis)
// one wave/node; col via int4 pairs; 8 row-gathers outstanding.
// ---------------------------------------------------------------------------
__global__ __launch_bounds__(256, 4) void k_spmv_bf(const int* __restrict__ rowptr,
                                                    const int* __restrict__ col,
                                                    const float* __restrict__ dis,
                                                    const u16* __restrict__ Xs,
                                                    u16* __restrict__ SXb, int n) {
  const int wave = threadIdx.x >> 6;
  const int lane = threadIdx.x & 63;
  const int i = blockIdx.x * 4 + wave;
  if (i >= n) return;
  int j = rowptr[i];
  const int end = rowptr[i + 1];
  float ax = 0.f, ay = 0.f;

#define ROWQ(c) (*(const unsigned int*)(Xs + (size_t)(c) * 128 + lane * 2))
#define ACC(q)  do { unsigned int _q = (q); \
                     ax += bf2f(_q & 0xffffu); ay += bf2f(_q >> 16); } while (0)

  for (; (j & 3) && j < end; ++j) ACC(ROWQ(col[j]));
  for (; j + 7 < end; j += 8) {
    int4 c0 = *(const int4*)(col + j);
    int4 c1 = *(const int4*)(col + j + 4);
    unsigned int q0 = ROWQ(c0.x), q1 = ROWQ(c0.y), q2 = ROWQ(c0.z), q3 = ROWQ(c0.w);
    unsigned int q4 = ROWQ(c1.x), q5 = ROWQ(c1.y), q6 = ROWQ(c1.z), q7 = ROWQ(c1.w);
    ACC(q0); ACC(q1); ACC(q2); ACC(q3);
    ACC(q4); ACC(q5); ACC(q6); ACC(q7);
  }
  if (j + 3 < end) {
    int4 c0 = *(const int4*)(col + j);
    unsigned int q0 = ROWQ(c0.x), q1 = ROWQ(c0.y), q2 = ROWQ(c0.z), q3 = ROWQ(c0.w);
    ACC(q0); ACC(q1); ACC(q2); ACC(q3);
    j += 4;
  }
  for (; j < end; ++j) ACC(ROWQ(col[j]));
#undef ROWQ
#undef ACC

  float di = dis[i];
  ax *= di;
  ay *= di;
  unsigned int o = (unsigned int)f2bf(ax) | ((unsigned int)f2bf(ay) << 16);
  *(unsigned int*)(SXb + (size_t)i * 128 + lane * 2) = o;
}

// ---------------------------------------------------------------------------
// MFMA fused layer, COLUMN-SPLIT:  v = lrelu( A0@W0 + A1@W1 + bias )
// grid (gM, 2); blockIdx.y picks cols [0,64) or [64,128). Per wave:
// 32 rows x 64 cols, acc[2][4], 64 MFMAs. NOT in-place safe (col halves of a
// row are written by different blocks) -> caller rotates buffers.
// outb: bf16 v; outs: bf16 dis[row]*v; outf: fp32 v.
// gfx950 16x16x32 mapping: A/B lane l -> row/col l&15, k (l>>4)*8+e;
//                          D lane l -> col l&15, row (l>>4)*4+e.
// ---------------------------------------------------------------------------
__global__ __launch_bounds__(256, 6) void k_mfma(const u16* __restrict__ A0,
                                                 const u16* __restrict__ A1,
                                                 const u16* __restrict__ W0T,
                                                 const u16* __restrict__ W1T,
                                                 const float* __restrict__ bias,
                                                 const float* __restrict__ dis,
                                                 u16* __restrict__ outb,
                                                 u16* __restrict__ outs,
                                                 float* __restrict__ outf, int M) {
  const int lane = threadIdx.x & 63;
  const int wv = threadIdx.x >> 6;
  const int row0 = blockIdx.x * 128 + wv * 32;
  const int c0off = blockIdx.y * 64;     // column half
  const int r = lane & 15;
  const int kg = lane >> 4;

  f32x4 acc[2][4];
#pragma unroll
  for (int a = 0; a < 2; ++a)
#pragma unroll
    for (int j = 0; j < 4; ++j) acc[a][j] = (f32x4){0.f, 0.f, 0.f, 0.f};

  const int ra0 = min(row0 + r, M - 1);
  const int ra1 = min(row0 + 16 + r, M - 1);

#pragma unroll
  for (int p = 0; p < 2; ++p) {
    const u16* A = p ? A1 : A0;
    const u16* WT = p ? W1T : W0T;
#pragma unroll
    for (int kk = 0; kk < 4; ++kk) {
      const int k0 = kk * 32 + kg * 8;
      bf16x8 a0 = *(const bf16x8*)(A + (size_t)ra0 * 128 + k0);
      bf16x8 a1 = *(const bf16x8*)(A + (size_t)ra1 * 128 + k0);
#pragma unroll
      for (int j = 0; j < 4; ++j) {
        bf16x8 b = *(const bf16x8*)(WT + (size_t)(c0off + j * 16 + r) * 128 + k0);
        acc[0][j] = __builtin_amdgcn_mfma_f32_16x16x32_bf16(a0, b, acc[0][j], 0, 0, 0);
        acc[1][j] = __builtin_amdgcn_mfma_f32_16x16x32_bf16(a1, b, acc[1][j], 0, 0, 0);
      }
    }
  }

#pragma unroll
  for (int rf = 0; rf < 2; ++rf)
#pragma unroll
    for (int e = 0; e < 4; ++e) {
      const int row = row0 + rf * 16 + kg * 4 + e;
      if (row >= M) continue;
      const float ds = outs ? dis[row] : 0.f;
#pragma unroll
      for (int j = 0; j < 4; ++j) {
        const int c = c0off + j * 16 + r;
        float v = acc[rf][j][e] + bias[c];
        v = (v > 0.f) ? v : 0.01f * v;
        if (outf) outf[(size_t)row * 128 + c] = v;
        if (outb) outb[(size_t)row * 128 + c] = f2bf(v);
        if (outs) outs[(size_t)row * 128 + c] = f2bf(v * ds);
      }
    }
}

// ---------------------------------------------------------------------------
// FC head via MFMA: y = h @ fcw + fcb. hb3 bf16 [M,128], fcT bf16 [64][128].
// hb3 may live in the y region (row-aligned): each wave reads its rows before
// storing them.
// ---------------------------------------------------------------------------
__global__ __launch_bounds__(256) void k_fc_mfma(const u16* __restrict__ hb3,
                                                 const u16* __restrict__ fcT,
                                                 const float* __restrict__ fcb,
                                                 float* __restrict__ y, int M) {
  const int lane = threadIdx.x & 63;
  const int wv = threadIdx.x >> 6;
  const int row0 = blockIdx.x * 128 + wv * 32;
  const int r = lane & 15;
  const int kg = lane >> 4;

  f32x4 acc[2][4];
#pragma unroll
  for (int a = 0; a < 2; ++a)
#pragma unroll
    for (int j = 0; j < 4; ++j) acc[a][j] = (f32x4){0.f, 0.f, 0.f, 0.f};

  const int ra0 = min(row0 + r, M - 1);
  const int ra1 = min(row0 + 16 + r, M - 1);

#pragma unroll
  for (int kk = 0; kk < 4; ++kk) {
    const int k0 = kk * 32 + kg * 8;
    bf16x8 a0 = *(const bf16x8*)(hb3 + (size_t)ra0 * 128 + k0);
    bf16x8 a1 = *(const bf16x8*)(hb3 + (size_t)ra1 * 128 + k0);
#pragma unroll
    for (int j = 0; j < 4; ++j) {
      bf16x8 b = *(const bf16x8*)(fcT + (size_t)(j * 16 + r) * 128 + k0);
      acc[0][j] = __builtin_amdgcn_mfma_f32_16x16x32_bf16(a0, b, acc[0][j], 0, 0, 0);
      acc[1][j] = __builtin_amdgcn_mfma_f32_16x16x32_bf16(a1, b, acc[1][j], 0, 0, 0);
    }
  }

#pragma unroll
  for (int rf = 0; rf < 2; ++rf)
#pragma unroll
    for (int e = 0; e < 4; ++e) {
      const int row = row0 + rf * 16 + kg * 4 + e;
      if (row >= M) continue;
#pragma unroll
      for (int j = 0; j < 4; ++j) {
        const int c = j * 16 + r;
        y[(size_t)row * 64 + c] = acc[rf][j][e] + fcb[c];
      }
    }
}

// ---------------------------------------------------------------------------

extern "C" void kernel_launch(void* const* d_in, const int* in_sizes, int n_in,
                              void* d_out, int out_size, void* d_ws, size_t ws_size,
                              hipStream_t stream) {
  const float* X  = (const float*)d_in[0];
  const int* ei   = (const int*)d_in[1];
  const float* gw1 = (const float*)d_in[3];
  const float* gb1 = (const float*)d_in[4];
  const float* lw1 = (const float*)d_in[5];
  const float* lb1 = (const float*)d_in[6];
  const float* gw2 = (const float*)d_in[7];
  const float* gb2 = (const float*)d_in[8];
  const float* lw2 = (const float*)d_in[9];
  const float* lb2 = (const float*)d_in[10];
  const float* gw3 = (const float*)d_in[11];
  const float* gb3 = (const float*)d_in[12];
  const float* lw3 = (const float*)d_in[13];
  const float* lb3 = (const float*)d_in[14];
  const float* fcw = (const float*)d_in[15];
  const float* fcb = (const float*)d_in[16];

  const int n = in_sizes[0] / 128;
  const int E = in_sizes[1] / 2;
  const int tot = E + n;
  const int B = (n + 255) >> 8;        // buckets (<=512)
  const int chunk = (E + G_CHUNKS - 1) / G_CHUNKS;

  char* ws = (char*)d_ws;
  size_t off = 0;
  auto alloc = [&](size_t bytes) -> void* {
    void* p = ws + off;
    off = (off + bytes + 255) & ~(size_t)255;
    return p;
  };
  int* ghist   = (int*)alloc((size_t)B * G_CHUNKS * 4);
  int* btot    = (int*)alloc(512 * 4);
  int* boff    = (int*)alloc((size_t)(B + 1) * 4);
  int* rowptr  = (int*)alloc((size_t)(n + 1) * 4);
  float* dis   = (float*)alloc((size_t)n * 4);
  int* col     = (int*)alloc((size_t)tot * 4);
  unsigned int* ebuf = (unsigned int*)alloc((size_t)E * 4);
  u16* Xb      = (u16*)alloc((size_t)n * 128 * 2);   // X bf16 -> h2 -> (dead)
  u16* Xs      = (u16*)alloc((size_t)n * 128 * 2);   // scaled gather src
  u16* SXb     = (u16*)alloc((size_t)n * 128 * 2);
  u16* WT      = (u16*)alloc((size_t)6 * 16384 * 2);
  u16* fcT     = (u16*)alloc((size_t)64 * 128 * 2);
  float* bias  = (float*)alloc(384 * 4);          // total ~92 MB

  float* outh = (float*)d_out;                 // [n,128] final h fp32
  float* outy = outh + (size_t)n * 128;        // [n,64]  final y fp32
  u16* hb = (u16*)outy;  // bf16 h1 / h3 in y-region (row-aligned with y);
                         // overwritten row-by-row by k_fc_mfma at the end.

  const int gM = (n + 127) / 128;
  const int gW = (n + 3) / 4;
  const int g8 = (n * 128 / 8 + 255) / 256;

  // ---- CSR build (counting sort) ----
  k_hist<<<G_CHUNKS, 256, 0, stream>>>(ei, ghist, E, B, chunk);
  k_hscan<<<B, 256, 0, stream>>>(ghist, btot);
  k_bscan<<<1, 512, 0, stream>>>(btot, boff, B, rowptr, n, E, tot);
  k_scatter<<<G_CHUNKS, 256, 0, stream>>>(ei, ghist, boff, ebuf, E, B, chunk);
  k_cfill<<<B, 256, 0, stream>>>(ebuf, boff, rowptr, col, dis, n);

  // ---- dtype prep (k_cvt needs dis -> after cfill) ----
  k_cvt<<<g8, 256, 0, stream>>>(X, dis, Xb, Xs, n * 128 / 8);
  k_prep<<<835, 128, 0, stream>>>(gw1, lw1, gw2, lw2, gw3, lw3,
                                  gb1, lb1, gb2, lb2, gb3, lb3, fcw,
                                  WT, bias, fcT);

  // ---- layer 1: gather Xs; A1=Xb -> h1:hb, h1s:Xs ----
  k_spmv_bf<<<gW, 256, 0, stream>>>(rowptr, col, dis, Xs, SXb, n);
  k_mfma<<<dim3(gM, 2), 256, 0, stream>>>(SXb, Xb, WT, WT + 16384, bias, dis,
                                          hb, Xs, nullptr, n);
  // ---- layer 2: gather h1s; A1=hb -> h2:Xb, h2s:Xs ----
  k_spmv_bf<<<gW, 256, 0, stream>>>(rowptr, col, dis, Xs, SXb, n);
  k_mfma<<<dim3(gM, 2), 256, 0, stream>>>(SXb, hb, WT + 2 * 16384, WT + 3 * 16384,
                                          bias + 128, dis, Xb, Xs, nullptr, n);
  // ---- layer 3: gather h2s; A1=Xb -> h3 fp32:outh, h3 bf16:hb ----
  k_spmv_bf<<<gW, 256, 0, stream>>>(rowptr, col, dis, Xs, SXb, n);
  k_mfma<<<dim3(gM, 2), 256, 0, stream>>>(SXb, Xb, WT + 4 * 16384, WT + 5 * 16384,
                                          bias + 256, dis, hb, nullptr, outh, n);
  // ---- FC head via MFMA (reads bf16 h3 in hb, overwrites with y) ----
  k_fc_mfma<<<gM, 256, 0, stream>>>(hb, fcT, fcb, outy, n);
}

// Round 11
// 442.995 us; speedup vs baseline: 1.5112x; 1.0627x over previous
//
#include <hip/hip_runtime.h>
#include <cstdint>
#include <cstddef>

// ---------------------------------------------------------------------------
// GCN 3-layer + FC head. Round 11: spmv 2-nodes/wave (512B per gather instr),
// mfma 4-way col-split (occupancy 24 -> 32 waves/CU cap).
// ---------------------------------------------------------------------------

typedef __attribute__((ext_vector_type(4))) float f32x4;
typedef __attribute__((ext_vector_type(8))) short bf16x8;
typedef unsigned short u16;

#define G_CHUNKS 256

__device__ __forceinline__ float bf2f(unsigned int u) {
  union { unsigned int i; float f; } v;
  v.i = u << 16;
  return v.f;
}
__device__ __forceinline__ u16 f2bf(float f) {
  union { float f; unsigned int i; } v;
  v.f = f;
  unsigned int i = v.i;
  return (u16)((i + 0x7FFFu + ((i >> 16) & 1u)) >> 16);  // RNE
}

// ---------------- CSR build: counting sort by dst bucket ----------------

__global__ __launch_bounds__(256) void k_hist(const int* __restrict__ ei,
                                              int* __restrict__ ghist,
                                              int E, int B, int chunk) {
  __shared__ int h[512];
  for (int t = threadIdx.x; t < B; t += 256) h[t] = 0;
  __syncthreads();
  const int g = blockIdx.x;
  const int beg = g * chunk;
  const int end = min(beg + chunk, E);
  for (int e = beg + threadIdx.x; e < end; e += 256)
    atomicAdd(&h[ei[E + e] >> 8], 1);
  __syncthreads();
  for (int t = threadIdx.x; t < B; t += 256) ghist[(size_t)t * G_CHUNKS + g] = h[t];
}

__global__ __launch_bounds__(256) void k_hscan(int* __restrict__ ghist,
                                               int* __restrict__ btot) {
  __shared__ int sm[256];
  int* p = ghist + (size_t)blockIdx.x * G_CHUNKS;
  const int t = threadIdx.x;
  int v = p[t];
  sm[t] = v;
  __syncthreads();
  for (int off = 1; off < 256; off <<= 1) {
    int u = (t >= off) ? sm[t - off] : 0;
    __syncthreads();
    sm[t] += u;
    __syncthreads();
  }
  p[t] = sm[t] - v;                     // exclusive
  if (t == 255) btot[blockIdx.x] = sm[255];
}

__global__ __launch_bounds__(512) void k_bscan(const int* __restrict__ btot,
                                               int* __restrict__ boff, int B,
                                               int* __restrict__ rowptr, int n,
                                               int E, int tot) {
  __shared__ int sm[512];
  const int t = threadIdx.x;
  int v = (t < B) ? btot[t] : 0;
  sm[t] = v;
  __syncthreads();
  for (int off = 1; off < 512; off <<= 1) {
    int u = (t >= off) ? sm[t - off] : 0;
    __syncthreads();
    sm[t] += u;
    __syncthreads();
  }
  if (t < B) boff[t] = sm[t] - v;       // exclusive
  if (t == 0) {
    boff[B] = E;
    rowptr[n] = tot;
  }
}

__global__ __launch_bounds__(256) void k_scatter(const int* __restrict__ ei,
                                                 const int* __restrict__ ghist,
                                                 const int* __restrict__ boff,
                                                 unsigned int* __restrict__ ebuf,
                                                 int E, int B, int chunk) {
  __shared__ int off[512];
  const int g = blockIdx.x;
  for (int t = threadIdx.x; t < B; t += 256)
    off[t] = boff[t] + ghist[(size_t)t * G_CHUNKS + g];
  __syncthreads();
  const int beg = g * chunk;
  const int end = min(beg + chunk, E);
  for (int e = beg + threadIdx.x; e < end; e += 256) {
    int s = ei[e];
    int d = ei[E + e];
    int pos = atomicAdd(&off[d >> 8], 1);
    ebuf[pos] = ((unsigned int)s << 8) | (unsigned int)(d & 255);
  }
}

__global__ __launch_bounds__(256) void k_cfill(const unsigned int* __restrict__ ebuf,
                                               const int* __restrict__ boff,
                                               int* __restrict__ rowptr,
                                               int* __restrict__ col,
                                               float* __restrict__ dis, int n) {
  __shared__ int cnt[256];
  __shared__ int fl[256];
  const int b = blockIdx.x;
  const int t = threadIdx.x;
  const int beg = boff[b];
  const int end = boff[b + 1];
  const int node0 = b << 8;
  const int nn = min(256, n - node0);
  cnt[t] = 0;
  __syncthreads();
  for (int e = beg + t; e < end; e += 256)
    atomicAdd(&cnt[ebuf[e] & 255u], 1);
  __syncthreads();
  int v = cnt[t];
  __shared__ int sm[256];
  sm[t] = v;
  __syncthreads();
  for (int off = 1; off < 256; off <<= 1) {
    int u = (t >= off) ? sm[t - off] : 0;
    __syncthreads();
    sm[t] += u;
    __syncthreads();
  }
  if (t < nn) {
    int excl = sm[t] - v;
    int rbase = beg + node0 + t + excl;   // earlier buckets' edges + self-loops
    int i = node0 + t;
    rowptr[i] = rbase;
    col[rbase] = i;                        // self-loop first
    fl[t] = rbase + 1;
    dis[i] = rsqrtf((float)(v + 1));
  }
  __syncthreads();
  for (int e = beg + t; e < end; e += 256) {
    unsigned int pk = ebuf[e];
    int pos = atomicAdd(&fl[pk & 255u], 1);
    col[pos] = (int)(pk >> 8);
  }
}

// ---------------- dtype prep ----------------

// X fp32 -> Xb (bf16) and Xs (bf16, pre-scaled by dis[row]); 8 elems/thread.
__global__ __launch_bounds__(256) void k_cvt(const float* __restrict__ src,
                                             const float* __restrict__ dis,
                                             u16* __restrict__ dstb,
                                             u16* __restrict__ dsts, int total8) {
  int i = blockIdx.x * 256 + threadIdx.x;
  if (i >= total8) return;
  size_t b = (size_t)i * 8;
  float ds = dis[i >> 4];               // 16 threads x 8 elems = one 128-row
  float4 a0 = *(const float4*)(src + b);
  float4 a1 = *(const float4*)(src + b + 4);
  u16 ob[8] = {f2bf(a0.x), f2bf(a0.y), f2bf(a0.z), f2bf(a0.w),
               f2bf(a1.x), f2bf(a1.y), f2bf(a1.z), f2bf(a1.w)};
  u16 os[8] = {f2bf(a0.x * ds), f2bf(a0.y * ds), f2bf(a0.z * ds), f2bf(a0.w * ds),
               f2bf(a1.x * ds), f2bf(a1.y * ds), f2bf(a1.z * ds), f2bf(a1.w * ds)};
  *(ulonglong2*)(dstb + b) = *(ulonglong2*)ob;
  *(ulonglong2*)(dsts + b) = *(ulonglong2*)os;
}

// blocks 0..767: WT[z][nr][k] = bf16(W_z[k][nr])
// blocks 768..770: bias sums; blocks 771..834: fcT[nr][k] = bf16(fcw[k][nr])
__global__ __launch_bounds__(128) void k_prep(const float* __restrict__ w0,
                                              const float* __restrict__ w1,
                                              const float* __restrict__ w2,
                                              const float* __restrict__ w3,
                                              const float* __restrict__ w4,
                                              const float* __restrict__ w5,
                                              const float* __restrict__ g1,
                                              const float* __restrict__ l1,
                                              const float* __restrict__ g2,
                                              const float* __restrict__ l2,
                                              const float* __restrict__ g3,
                                              const float* __restrict__ l3,
                                              const float* __restrict__ fcw,
                                              u16* __restrict__ wt,
                                              float* __restrict__ bias,
                                              u16* __restrict__ fcT) {
  int bx = blockIdx.x;
  if (bx < 768) {
    int z = bx >> 7, nr = bx & 127, k = threadIdx.x;
    const float* Ws[6] = {w0, w1, w2, w3, w4, w5};
    wt[(size_t)z * 16384 + nr * 128 + k] = f2bf(Ws[z][k * 128 + nr]);
  } else if (bx < 771) {
    int t = (bx - 768) * 128 + threadIdx.x;
    if (t < 384) {
      const float* gs[3] = {g1, g2, g3};
      const float* ls[3] = {l1, l2, l3};
      bias[t] = gs[t >> 7][t & 127] + ls[t >> 7][t & 127];
    }
  } else {
    int nr = bx - 771;                 // 0..63
    int k = threadIdx.x;
    fcT[nr * 128 + k] = f2bf(fcw[k * 64 + nr]);
  }
}

// ---------------------------------------------------------------------------
// SXb[i] = bf16( dis[i] * sum_j Xs[col[j], :] )   (Xs pre-scaled by dis)
// 2 nodes per wave: 32 lanes/node, uint2 (4 bf16)/lane -> one load instr
// gathers 512B across two rows. 8-edge unroll per node.
// ---------------------------------------------------------------------------
__global__ __launch_bounds__(256, 8) void k_spmv_bf(const int* __restrict__ rowptr,
                                                    const int* __restrict__ col,
                                                    const float* __restrict__ dis,
                                                    const u16* __restrict__ Xs,
                                                    u16* __restrict__ SXb, int n) {
  const int tid = threadIdx.x;
  const int half = (tid >> 5) & 1;      // which node within the wave
  const int sub = tid & 31;             // lane within node (4 bf16 each)
  const int i = blockIdx.x * 8 + (tid >> 6) * 2 + half;
  if (i >= n) return;
  int j = rowptr[i];
  const int end = rowptr[i + 1];
  float a0 = 0.f, a1 = 0.f, a2 = 0.f, a3 = 0.f;

#define ROWQ(c) (*(const uint2*)(Xs + (size_t)(c) * 128 + sub * 4))
#define ACC(q)  do { uint2 _q = (q); \
                     a0 += bf2f(_q.x & 0xffffu); a1 += bf2f(_q.x >> 16); \
                     a2 += bf2f(_q.y & 0xffffu); a3 += bf2f(_q.y >> 16); } while (0)

  for (; (j & 3) && j < end; ++j) ACC(ROWQ(col[j]));
  for (; j + 7 < end; j += 8) {
    int4 c0 = *(const int4*)(col + j);
    int4 c1 = *(const int4*)(col + j + 4);
    uint2 q0 = ROWQ(c0.x), q1 = ROWQ(c0.y), q2 = ROWQ(c0.z), q3 = ROWQ(c0.w);
    uint2 q4 = ROWQ(c1.x), q5 = ROWQ(c1.y), q6 = ROWQ(c1.z), q7 = ROWQ(c1.w);
    ACC(q0); ACC(q1); ACC(q2); ACC(q3);
    ACC(q4); ACC(q5); ACC(q6); ACC(q7);
  }
  if (j + 3 < end) {
    int4 c0 = *(const int4*)(col + j);
    uint2 q0 = ROWQ(c0.x), q1 = ROWQ(c0.y), q2 = ROWQ(c0.z), q3 = ROWQ(c0.w);
    ACC(q0); ACC(q1); ACC(q2); ACC(q3);
    j += 4;
  }
  for (; j < end; ++j) ACC(ROWQ(col[j]));
#undef ROWQ
#undef ACC

  const float di = dis[i];
  uint2 o;
  o.x = (unsigned int)f2bf(a0 * di) | ((unsigned int)f2bf(a1 * di) << 16);
  o.y = (unsigned int)f2bf(a2 * di) | ((unsigned int)f2bf(a3 * di) << 16);
  *(uint2*)(SXb + (size_t)i * 128 + sub * 4) = o;
}

// ---------------------------------------------------------------------------
// MFMA fused layer, 4-way COLUMN-SPLIT:  v = lrelu( A0@W0 + A1@W1 + bias )
// grid (gM, 4); blockIdx.y picks a 32-col slice. Per wave: 32 rows x 32 cols,
// acc[2][2], 32 MFMAs. NOT in-place safe -> caller rotates buffers.
// outb: bf16 v; outs: bf16 dis[row]*v; outf: fp32 v.
// gfx950 16x16x32 mapping: A/B lane l -> row/col l&15, k (l>>4)*8+e;
//                          D lane l -> col l&15, row (l>>4)*4+e.
// ---------------------------------------------------------------------------
__global__ __launch_bounds__(256, 8) void k_mfma(const u16* __restrict__ A0,
                                                 const u16* __restrict__ A1,
                                                 const u16* __restrict__ W0T,
                                                 const u16* __restrict__ W1T,
                                                 const float* __restrict__ bias,
                                                 const float* __restrict__ dis,
                                                 u16* __restrict__ outb,
                                                 u16* __restrict__ outs,
                                                 float* __restrict__ outf, int M) {
  const int lane = threadIdx.x & 63;
  const int wv = threadIdx.x >> 6;
  const int row0 = blockIdx.x * 128 + wv * 32;
  const int c0off = blockIdx.y * 32;     // column slice
  const int r = lane & 15;
  const int kg = lane >> 4;

  f32x4 acc[2][2];
#pragma unroll
  for (int a = 0; a < 2; ++a)
#pragma unroll
    for (int j = 0; j < 2; ++j) acc[a][j] = (f32x4){0.f, 0.f, 0.f, 0.f};

  const int ra0 = min(row0 + r, M - 1);
  const int ra1 = min(row0 + 16 + r, M - 1);

#pragma unroll
  for (int p = 0; p < 2; ++p) {
    const u16* A = p ? A1 : A0;
    const u16* WT = p ? W1T : W0T;
#pragma unroll
    for (int kk = 0; kk < 4; ++kk) {
      const int k0 = kk * 32 + kg * 8;
      bf16x8 a0 = *(const bf16x8*)(A + (size_t)ra0 * 128 + k0);
      bf16x8 a1 = *(const bf16x8*)(A + (size_t)ra1 * 128 + k0);
#pragma unroll
      for (int j = 0; j < 2; ++j) {
        bf16x8 b = *(const bf16x8*)(WT + (size_t)(c0off + j * 16 + r) * 128 + k0);
        acc[0][j] = __builtin_amdgcn_mfma_f32_16x16x32_bf16(a0, b, acc[0][j], 0, 0, 0);
        acc[1][j] = __builtin_amdgcn_mfma_f32_16x16x32_bf16(a1, b, acc[1][j], 0, 0, 0);
      }
    }
  }

#pragma unroll
  for (int rf = 0; rf < 2; ++rf)
#pragma unroll
    for (int e = 0; e < 4; ++e) {
      const int row = row0 + rf * 16 + kg * 4 + e;
      if (row >= M) continue;
      const float ds = outs ? dis[row] : 0.f;
#pragma unroll
      for (int j = 0; j < 2; ++j) {
        const int c = c0off + j * 16 + r;
        float v = acc[rf][j][e] + bias[c];
        v = (v > 0.f) ? v : 0.01f * v;
        if (outf) outf[(size_t)row * 128 + c] = v;
        if (outb) outb[(size_t)row * 128 + c] = f2bf(v);
        if (outs) outs[(size_t)row * 128 + c] = f2bf(v * ds);
      }
    }
}

// ---------------------------------------------------------------------------
// FC head via MFMA: y = h @ fcw + fcb. hb3 bf16 [M,128], fcT bf16 [64][128].
// hb3 may live in the y region (row-aligned): each wave reads its rows before
// storing them.
// ---------------------------------------------------------------------------
__global__ __launch_bounds__(256) void k_fc_mfma(const u16* __restrict__ hb3,
                                                 const u16* __restrict__ fcT,
                                                 const float* __restrict__ fcb,
                                                 float* __restrict__ y, int M) {
  const int lane = threadIdx.x & 63;
  const int wv = threadIdx.x >> 6;
  const int row0 = blockIdx.x * 128 + wv * 32;
  const int r = lane & 15;
  const int kg = lane >> 4;

  f32x4 acc[2][4];
#pragma unroll
  for (int a = 0; a < 2; ++a)
#pragma unroll
    for (int j = 0; j < 4; ++j) acc[a][j] = (f32x4){0.f, 0.f, 0.f, 0.f};

  const int ra0 = min(row0 + r, M - 1);
  const int ra1 = min(row0 + 16 + r, M - 1);

#pragma unroll
  for (int kk = 0; kk < 4; ++kk) {
    const int k0 = kk * 32 + kg * 8;
    bf16x8 a0 = *(const bf16x8*)(hb3 + (size_t)ra0 * 128 + k0);
    bf16x8 a1 = *(const bf16x8*)(hb3 + (size_t)ra1 * 128 + k0);
#pragma unroll
    for (int j = 0; j < 4; ++j) {
      bf16x8 b = *(const bf16x8*)(fcT + (size_t)(j * 16 + r) * 128 + k0);
      acc[0][j] = __builtin_amdgcn_mfma_f32_16x16x32_bf16(a0, b, acc[0][j], 0, 0, 0);
      acc[1][j] = __builtin_amdgcn_mfma_f32_16x16x32_bf16(a1, b, acc[1][j], 0, 0, 0);
    }
  }

#pragma unroll
  for (int rf = 0; rf < 2; ++rf)
#pragma unroll
    for (int e = 0; e < 4; ++e) {
      const int row = row0 + rf * 16 + kg * 4 + e;
      if (row >= M) continue;
#pragma unroll
      for (int j = 0; j < 4; ++j) {
        const int c = j * 16 + r;
        y[(size_t)row * 64 + c] = acc[rf][j][e] + fcb[c];
      }
    }
}

// ---------------------------------------------------------------------------

extern "C" void kernel_launch(void* const* d_in, const int* in_sizes, int n_in,
                              void* d_out, int out_size, void* d_ws, size_t ws_size,
                              hipStream_t stream) {
  const float* X  = (const float*)d_in[0];
  const int* ei   = (const int*)d_in[1];
  const float* gw1 = (const float*)d_in[3];
  const float* gb1 = (const float*)d_in[4];
  const float* lw1 = (const float*)d_in[5];
  const float* lb1 = (const float*)d_in[6];
  const float* gw2 = (const float*)d_in[7];
  const float* gb2 = (const float*)d_in[8];
  const float* lw2 = (const float*)d_in[9];
  const float* lb2 = (const float*)d_in[10];
  const float* gw3 = (const float*)d_in[11];
  const float* gb3 = (const float*)d_in[12];
  const float* lw3 = (const float*)d_in[13];
  const float* lb3 = (const float*)d_in[14];
  const float* fcw = (const float*)d_in[15];
  const float* fcb = (const float*)d_in[16];

  const int n = in_sizes[0] / 128;
  const int E = in_sizes[1] / 2;
  const int tot = E + n;
  const int B = (n + 255) >> 8;        // buckets (<=512)
  const int chunk = (E + G_CHUNKS - 1) / G_CHUNKS;

  char* ws = (char*)d_ws;
  size_t off = 0;
  auto alloc = [&](size_t bytes) -> void* {
    void* p = ws + off;
    off = (off + bytes + 255) & ~(size_t)255;
    return p;
  };
  int* ghist   = (int*)alloc((size_t)B * G_CHUNKS * 4);
  int* btot    = (int*)alloc(512 * 4);
  int* boff    = (int*)alloc((size_t)(B + 1) * 4);
  int* rowptr  = (int*)alloc((size_t)(n + 1) * 4);
  float* dis   = (float*)alloc((size_t)n * 4);
  int* col     = (int*)alloc((size_t)tot * 4);
  unsigned int* ebuf = (unsigned int*)alloc((size_t)E * 4);
  u16* Xb      = (u16*)alloc((size_t)n * 128 * 2);   // X bf16 -> h2 -> (dead)
  u16* Xs      = (u16*)alloc((size_t)n * 128 * 2);   // scaled gather src
  u16* SXb     = (u16*)alloc((size_t)n * 128 * 2);
  u16* WT      = (u16*)alloc((size_t)6 * 16384 * 2);
  u16* fcT     = (u16*)alloc((size_t)64 * 128 * 2);
  float* bias  = (float*)alloc(384 * 4);          // total ~92 MB

  float* outh = (float*)d_out;                 // [n,128] final h fp32
  float* outy = outh + (size_t)n * 128;        // [n,64]  final y fp32
  u16* hb = (u16*)outy;  // bf16 h1 / h3 in y-region (row-aligned with y);
                         // overwritten row-by-row by k_fc_mfma at the end.

  const int gM = (n + 127) / 128;
  const int gW = (n + 7) / 8;          // 8 nodes per block (2 per wave)
  const int g8 = (n * 128 / 8 + 255) / 256;

  // ---- CSR build (counting sort) ----
  k_hist<<<G_CHUNKS, 256, 0, stream>>>(ei, ghist, E, B, chunk);
  k_hscan<<<B, 256, 0, stream>>>(ghist, btot);
  k_bscan<<<1, 512, 0, stream>>>(btot, boff, B, rowptr, n, E, tot);
  k_scatter<<<G_CHUNKS, 256, 0, stream>>>(ei, ghist, boff, ebuf, E, B, chunk);
  k_cfill<<<B, 256, 0, stream>>>(ebuf, boff, rowptr, col, dis, n);

  // ---- dtype prep (k_cvt needs dis -> after cfill) ----
  k_cvt<<<g8, 256, 0, stream>>>(X, dis, Xb, Xs, n * 128 / 8);
  k_prep<<<835, 128, 0, stream>>>(gw1, lw1, gw2, lw2, gw3, lw3,
                                  gb1, lb1, gb2, lb2, gb3, lb3, fcw,
                                  WT, bias, fcT);

  // ---- layer 1: gather Xs; A1=Xb -> h1:hb, h1s:Xs ----
  k_spmv_bf<<<gW, 256, 0, stream>>>(rowptr, col, dis, Xs, SXb, n);
  k_mfma<<<dim3(gM, 4), 256, 0, stream>>>(SXb, Xb, WT, WT + 16384, bias, dis,
                                          hb, Xs, nullptr, n);
  // ---- layer 2: gather h1s; A1=hb -> h2:Xb, h2s:Xs ----
  k_spmv_bf<<<gW, 256, 0, stream>>>(rowptr, col, dis, Xs, SXb, n);
  k_mfma<<<dim3(gM, 4), 256, 0, stream>>>(SXb, hb, WT + 2 * 16384, WT + 3 * 16384,
                                          bias + 128, dis, Xb, Xs, nullptr, n);
  // ---- layer 3: gather h2s; A1=Xb -> h3 fp32:outh, h3 bf16:hb ----
  k_spmv_bf<<<gW, 256, 0, stream>>>(rowptr, col, dis, Xs, SXb, n);
  k_mfma<<<dim3(gM, 4), 256, 0, stream>>>(SXb, Xb, WT + 4 * 16384, WT + 5 * 16384,
                                          bias + 256, dis, hb, nullptr, outh, n);
  // ---- FC head via MFMA (reads bf16 h3 in hb, overwrites with y) ----
  k_fc_mfma<<<gM, 256, 0, stream>>>(hb, fcT, fcb, outy, n);
}